// Round 1
// baseline (379.712 us; speedup 1.0000x reference)
//
#include <hip/hip_runtime.h>

// PILayer: out = tanh((prop[idx_i] + basis + prop[idx_j]) @ W1 + b1) @ W2 + b2
// E=320000, D_IN=128, D_HID=256, D_OUT=128. fp32 in/out, fp16 MFMA internally.

#define N_EDGES 320000
#define DI 128
#define DH 256
#define DO 128
#define TM 64   // edges per block tile

typedef _Float16 half8v __attribute__((ext_vector_type(8)));
typedef _Float16 half4v __attribute__((ext_vector_type(4)));
typedef float floatx16 __attribute__((ext_vector_type(16)));

__device__ __forceinline__ float fast_tanh(float x) {
    float ax = __builtin_fabsf(x);
    float e = __expf(2.0f * ax);                       // v_mul + v_exp_f32
    float t = 1.0f - 2.0f * __builtin_amdgcn_rcpf(e + 1.0f);
    return __builtin_copysignf(t, x);
}

// ---------------------------------------------------------------------------
// Prologue: transpose+convert W1[128][256] -> W1T fp16 [256][128],
//                             W2[256][128] -> W2T fp16 [128][256]
// 64 blocks of 256 threads, one 32x32 tile each, LDS transpose.
// ---------------------------------------------------------------------------
__global__ __launch_bounds__(256) void wconvert(
    const float* __restrict__ W1, const float* __restrict__ W2,
    _Float16* __restrict__ W1T, _Float16* __restrict__ W2T)
{
    __shared__ float sT[32][33];
    int b = blockIdx.x;
    const float* src; _Float16* dst; int R, C, r0, c0;
    if (b < 32) { src = W1; dst = W1T; R = DI;  C = DH; r0 = (b & 3) * 32;  c0 = (b >> 2) * 32; }
    else { b -= 32; src = W2; dst = W2T; R = DH; C = DO; r0 = (b & 7) * 32; c0 = (b >> 3) * 32; }

    const int tid = threadIdx.x;
    const int cc = tid & 31, rr = tid >> 5;
    #pragma unroll
    for (int p = 0; p < 4; ++p) {
        int r = rr + p * 8;
        sT[r][cc] = src[(size_t)(r0 + r) * C + c0 + cc];
    }
    __syncthreads();
    #pragma unroll
    for (int p = 0; p < 4; ++p) {
        int c = rr + p * 8;                 // dst row = src col
        dst[(size_t)(c0 + c) * R + r0 + cc] = (_Float16)sT[cc][c];
    }
}

// ---------------------------------------------------------------------------
// Main fused kernel: one block = one 64-edge tile, 4 waves.
//   stage inter(fp16) -> GEMM1 (B from global W1T) -> tanh -> sH
//   -> GEMM2 (B from global W2T) -> +b2 -> store
// mfma_f32_32x32x16_f16: A lane l: m=l&31, k=(l>>5)*8+j (contig 8)
//                        B lane l: n=l&31, k=(l>>5)*8+j (contig 8 in W^T)
//                        C/D lane l reg r: col=l&31, row=(r&3)+8*(r>>2)+4*(l>>5)
// ---------------------------------------------------------------------------
__global__ __launch_bounds__(256) void pilayer_main(
    const int* __restrict__ idx_i, const int* __restrict__ idx_j,
    const float* __restrict__ prop, const float* __restrict__ basis,
    const _Float16* __restrict__ W1T, const float* __restrict__ b1,
    const _Float16* __restrict__ W2T, const float* __restrict__ b2,
    float* __restrict__ out)
{
    // stride pads: +8 fp16 keeps rows 16B-aligned and gives the 68-dword
    // (mod 32 = 4) bank pattern -> conflict-free b128 reads (m97 pattern)
    __shared__ _Float16 sA[TM][DI + 8];    // 64 x 136 = 17408 B
    __shared__ _Float16 sH[TM][DH + 8];    // 64 x 264 = 33792 B

    const int tid = threadIdx.x;
    const int e0 = blockIdx.x * TM;

    // ---- stage inter = prop[i] + basis + prop[j] as fp16 into sA ----
    {
        const int c4 = (tid & 31) * 4;     // col
        const int r0 = tid >> 5;           // 0..7
        #pragma unroll
        for (int p = 0; p < 8; ++p) {
            const int r = r0 + p * 8;
            const int e = e0 + r;
            const int ii = idx_i[e], jj = idx_j[e];
            const float4 a = *(const float4*)(prop  + (size_t)ii * DI + c4);
            const float4 bv = *(const float4*)(prop + (size_t)jj * DI + c4);
            const float4 c = *(const float4*)(basis + (size_t)e  * DI + c4);
            half4v hv;
            hv[0] = (_Float16)(a.x + bv.x + c.x);
            hv[1] = (_Float16)(a.y + bv.y + c.y);
            hv[2] = (_Float16)(a.z + bv.z + c.z);
            hv[3] = (_Float16)(a.w + bv.w + c.w);
            *(half4v*)(&sA[r][c4]) = hv;
        }
    }
    __syncthreads();

    const int w  = tid >> 6;       // wave 0..3
    const int l  = tid & 63;
    const int lm = l & 31;         // m / n within 32x32 tile
    const int lk = (l >> 5) * 8;   // k sub-offset
    const int rowq = 4 * (l >> 5); // row quad base for C/D layout

    // ---- GEMM1: h[64 x 256], wave w owns cols [w*64, w*64+64) (2 n-tiles) ----
    floatx16 hacc[2][2] = {};      // [mt][nt]
    {
        const _Float16* w1p = W1T + (size_t)(w * 64 + lm) * DI + lk;  // nt=0; nt=1 at +32*DI
        #pragma unroll 4
        for (int kt = 0; kt < 8; ++kt) {
            const int ko = kt * 16;
            half8v a0 = *(const half8v*)(&sA[lm][ko + lk]);
            half8v a1 = *(const half8v*)(&sA[32 + lm][ko + lk]);
            half8v b0 = *(const half8v*)(w1p + ko);
            half8v b1f = *(const half8v*)(w1p + 32 * DI + ko);
            hacc[0][0] = __builtin_amdgcn_mfma_f32_32x32x16_f16(a0, b0,  hacc[0][0], 0, 0, 0);
            hacc[1][0] = __builtin_amdgcn_mfma_f32_32x32x16_f16(a1, b0,  hacc[1][0], 0, 0, 0);
            hacc[0][1] = __builtin_amdgcn_mfma_f32_32x32x16_f16(a0, b1f, hacc[0][1], 0, 0, 0);
            hacc[1][1] = __builtin_amdgcn_mfma_f32_32x32x16_f16(a1, b1f, hacc[1][1], 0, 0, 0);
        }
    }

    // ---- bias + tanh, write h to sH (C-layout -> memory layout) ----
    {
        const float bias0 = b1[w * 64 + lm];
        const float bias1 = b1[w * 64 + 32 + lm];
        #pragma unroll
        for (int mt = 0; mt < 2; ++mt) {
            #pragma unroll
            for (int r = 0; r < 16; ++r) {
                const int row = mt * 32 + (r & 3) + 8 * (r >> 2) + rowq;
                sH[row][w * 64 + lm]      = (_Float16)fast_tanh(hacc[mt][0][r] + bias0);
                sH[row][w * 64 + 32 + lm] = (_Float16)fast_tanh(hacc[mt][1][r] + bias1);
            }
        }
    }
    __syncthreads();

    // ---- GEMM2: out[64 x 128], wave w owns cols [w*32, w*32+32) (1 n-tile) ----
    floatx16 oacc[2] = {};
    {
        const _Float16* w2p = W2T + (size_t)(w * 32 + lm) * DH + lk;
        #pragma unroll 4
        for (int kt = 0; kt < 16; ++kt) {
            const int ko = kt * 16;
            half8v a0 = *(const half8v*)(&sH[lm][ko + lk]);
            half8v a1 = *(const half8v*)(&sH[32 + lm][ko + lk]);
            half8v bb = *(const half8v*)(w2p + ko);
            oacc[0] = __builtin_amdgcn_mfma_f32_32x32x16_f16(a0, bb, oacc[0], 0, 0, 0);
            oacc[1] = __builtin_amdgcn_mfma_f32_32x32x16_f16(a1, bb, oacc[1], 0, 0, 0);
        }
    }

    // ---- epilogue: + b2, store fp32 ----
    {
        const int col = w * 32 + lm;
        const float bias = b2[col];
        #pragma unroll
        for (int mt = 0; mt < 2; ++mt) {
            #pragma unroll
            for (int r = 0; r < 16; ++r) {
                const int row = e0 + mt * 32 + (r & 3) + 8 * (r >> 2) + rowq;
                out[(size_t)row * DO + col] = oacc[mt][r] + bias;
            }
        }
    }
}

extern "C" void kernel_launch(void* const* d_in, const int* in_sizes, int n_in,
                              void* d_out, int out_size, void* d_ws, size_t ws_size,
                              hipStream_t stream) {
    const int*   idx_i = (const int*)d_in[0];
    const int*   idx_j = (const int*)d_in[1];
    const float* prop  = (const float*)d_in[2];
    const float* basis = (const float*)d_in[3];
    const float* W1    = (const float*)d_in[4];
    const float* b1    = (const float*)d_in[5];
    const float* W2    = (const float*)d_in[6];
    const float* b2    = (const float*)d_in[7];
    float* out = (float*)d_out;

    _Float16* W1T = (_Float16*)d_ws;            // [256][128] = 64 KB
    _Float16* W2T = W1T + (size_t)DI * DH;      // [128][256] = 64 KB

    wconvert<<<64, 256, 0, stream>>>(W1, W2, W1T, W2T);
    pilayer_main<<<N_EDGES / TM, 256, 0, stream>>>(idx_i, idx_j, prop, basis,
                                                   W1T, b1, W2T, b2, out);
}